// Round 18
// baseline (1229.196 us; speedup 1.0000x reference)
//
#include <hip/hip_runtime.h>
#include <hip/hip_bf16.h>

#define N_ATOMS 10000
#define N_EDGES 320000
#define H 256
#define H3 768
#define N_RBF 20
#define LN_EPS 1e-5f

typedef __attribute__((ext_vector_type(8))) short bf16x8;
typedef __attribute__((ext_vector_type(4))) float f32x4;
#define MFMA16 __builtin_amdgcn_mfma_f32_16x16x32_bf16

__device__ __forceinline__ float silu_f(float x) { return x / (1.f + __expf(-x)); }

__device__ __forceinline__ unsigned short f2bf(float x) {
    union { float f; unsigned u; } v; v.f = x;
    unsigned r = v.u + 0x7fff + ((v.u >> 16) & 1);
    return (unsigned short)(r >> 16);
}
__device__ __forceinline__ float bf2f(unsigned short b) {
    union { unsigned u; float f; } v; v.u = ((unsigned)b) << 16; return v.f;
}

// ---------------- LayerNorm: one block (256 thr) per atom ----------------
__global__ __launch_bounds__(256) void k_ln(const float* __restrict__ s,
                                            const float* __restrict__ g,
                                            const float* __restrict__ b,
                                            float* __restrict__ sn) {
    int a = blockIdx.x, t = threadIdx.x;
    float x = s[(size_t)a * H + t];
    __shared__ float red[4];
    float v = x;
    for (int o = 32; o > 0; o >>= 1) v += __shfl_down(v, o);
    if ((t & 63) == 0) red[t >> 6] = v;
    __syncthreads();
    float mu = (red[0] + red[1] + red[2] + red[3]) * (1.f / H);
    float dx = x - mu;
    __syncthreads();
    v = dx * dx;
    for (int o = 32; o > 0; o >>= 1) v += __shfl_down(v, o);
    if ((t & 63) == 0) red[t >> 6] = v;
    __syncthreads();
    float var = (red[0] + red[1] + red[2] + red[3]) * (1.f / H);
    float rs = rsqrtf(var + LN_EPS);
    sn[(size_t)a * H + t] = dx * rs * g[t] + b[t];
}

// ---------------- fp32 tiled GEMM: C = [silu](A@B + bias) ----------------
template <int DO_SILU, int IN_BF16, int OUT_BF16>
__global__ __launch_bounds__(256) void k_gemm(const void* __restrict__ Av,
                                              const float* __restrict__ B,
                                              const float* __restrict__ bias,
                                              void* __restrict__ Cv,
                                              int M, int N, int K) {
    const int BM = 64, BN = 64, BK = 16;
    __shared__ float As[BK][BM + 1];
    __shared__ float Bs[BK][BN + 1];
    int tid = threadIdx.x;
    int m0 = blockIdx.x * BM, n0 = blockIdx.y * BN;
    int ty = tid >> 4, tx = tid & 15;
    float acc[4][4] = {};
    for (int k0 = 0; k0 < K; k0 += BK) {
        {
            int kk = tid & 15, mm = tid >> 4;
            for (int r = 0; r < 4; r++) {
                int m = mm + r * 16;
                int gm = m0 + m;
                float a = 0.f;
                if (gm < M) {
                    if (IN_BF16) a = bf2f(((const unsigned short*)Av)[(size_t)gm * K + k0 + kk]);
                    else         a = ((const float*)Av)[(size_t)gm * K + k0 + kk];
                }
                As[kk][m] = a;
            }
        }
        {
            int n = tid & 63, kk = tid >> 6;
            for (int r = 0; r < 4; r++) {
                int k = kk + r * 4;
                Bs[k][n] = B[(size_t)(k0 + k) * N + n0 + n];
            }
        }
        __syncthreads();
        for (int k = 0; k < BK; k++) {
            float a[4], bb[4];
            for (int i = 0; i < 4; i++) a[i] = As[k][ty * 4 + i];
            for (int j = 0; j < 4; j++) bb[j] = Bs[k][tx * 4 + j];
            for (int i = 0; i < 4; i++)
                for (int j = 0; j < 4; j++) acc[i][j] += a[i] * bb[j];
        }
        __syncthreads();
    }
    for (int i = 0; i < 4; i++) {
        int gm = m0 + ty * 4 + i;
        if (gm >= M) continue;
        for (int j = 0; j < 4; j++) {
            int gn = n0 + tx * 4 + j;
            float y = acc[i][j] + bias[gn];
            if (DO_SILU) y = silu_f(y);
            if (OUT_BF16) ((unsigned short*)Cv)[(size_t)gm * N + gn] = f2bf(y);
            else          ((float*)Cv)[(size_t)gm * N + gn] = y;
        }
    }
}

// ---------------- weight prep ----------------
// fw2frag: fragment-ordered bf16 table for CB=32 tiles.
// record u = ((ct*8+q)*6+nf)*64+lane, 8 shorts: fw2[k0+j][n_glob],
// k0=q*32+(lane>>4)*8, n=nf*16+(lane&15) in [0,96),
// n_glob=(n>>5)*256 + ct*32 + (n&31). 393,216 B total.
__global__ __launch_bounds__(256) void k_prep_fw2frag(const float* __restrict__ fw2,
                                                      unsigned short* __restrict__ fw2frag) {
    int u = blockIdx.x * 256 + threadIdx.x;       // 0..24575
    int lane = u & 63;
    int rest = u >> 6;                            // 0..383
    int nf = rest % 6;
    int q = (rest / 6) % 8;
    int ct = rest / 48;
    int n = nf * 16 + (lane & 15);
    int n_glob = (n >> 5) * 256 + ct * 32 + (n & 31);
    int k0 = q * 32 + (lane >> 4) * 8;
    unsigned short rec[8];
#pragma unroll
    for (int j = 0; j < 8; ++j)
        rec[j] = f2bf(fw2[(size_t)(k0 + j) * H3 + n_glob]);
    ushort4* dst = (ushort4*)(fw2frag + (size_t)u * 8);
    dst[0] = make_ushort4(rec[0], rec[1], rec[2], rec[3]);
    dst[1] = make_ushort4(rec[4], rec[5], rec[6], rec[7]);
}
__global__ __launch_bounds__(256) void k_prep_fw1t2(const float* __restrict__ fw1,
                                                    unsigned short* __restrict__ fw1t2) {
    int c = threadIdx.x;
    for (int k = 0; k < 32; k++) {
        float wv = (k < N_RBF) ? fw1[k * H + c] : 0.f;
        unsigned short hi = f2bf(wv);
        unsigned short lo = f2bf(wv - bf2f(hi));
        fw1t2[c * 64 + k] = hi;
        fw1t2[c * 64 + 32 + k] = lo;
    }
}
// v (fp32, 7.68M elems) -> bf16 copy for the edge-kernel gathers
__global__ __launch_bounds__(256) void k_prep_vbf(const float* __restrict__ v,
                                                  unsigned short* __restrict__ vbf) {
    int i = blockIdx.x * 1024 + threadIdx.x * 4;
    float4 a = *(const float4*)(v + i);
    ushort4 o;
    o.x = f2bf(a.x); o.y = f2bf(a.y); o.z = f2bf(a.z); o.w = f2bf(a.w);
    *(ushort4*)(vbf + i) = o;
}

// ---------------- counting sort by idx_i ----------------
__global__ __launch_bounds__(256) void k_hist(const int* __restrict__ idx_i,
                                              int* __restrict__ counts) {
    int e = blockIdx.x * 256 + threadIdx.x;
    if (e < N_EDGES) atomicAdd(&counts[idx_i[e]], 1);
}
__global__ __launch_bounds__(256) void k_scan(const int* __restrict__ counts,
                                              int* __restrict__ rowstart) {
    __shared__ int part[257];
    int t = threadIdx.x;
    const int PER = 40;
    int s = 0;
    for (int r = 0; r < PER; ++r) { int i = t * PER + r; if (i < N_ATOMS) s += counts[i]; }
    part[t + 1] = s;
    if (t == 0) part[0] = 0;
    __syncthreads();
    for (int off = 1; off < 256; off <<= 1) {
        int v = (t + 1 > off) ? part[t + 1 - off] : 0;
        __syncthreads();
        part[t + 1] += v;
        __syncthreads();
    }
    int run = part[t];
    for (int r = 0; r < PER; ++r) {
        int i = t * PER + r;
        if (i < N_ATOMS) { rowstart[i] = run; run += counts[i]; }
    }
    if (t == 255) rowstart[N_ATOMS] = run;
}
// scatter with fused gather: one pass builds perm + sorted edge metadata
__global__ __launch_bounds__(256) void k_scatter(const int* __restrict__ idx_i,
                                                 const int* __restrict__ idx_j,
                                                 const float* __restrict__ f_cut,
                                                 const float* __restrict__ dir_ij,
                                                 const float* __restrict__ inv_ptr,
                                                 const int* __restrict__ rowstart,
                                                 int* __restrict__ cursor,
                                                 int* __restrict__ perm,
                                                 int* __restrict__ si, int* __restrict__ sj,
                                                 float* __restrict__ sfc,
                                                 float* __restrict__ sdir) {
    int e = blockIdx.x * 256 + threadIdx.x;
    if (e >= N_EDGES) return;
    int i = idx_i[e];
    int p = rowstart[i] + atomicAdd(&cursor[i], 1);
    perm[p] = e;
    si[p] = i;
    sj[p] = idx_j[e];
    sfc[p] = f_cut[e] * inv_ptr[0];
    sdir[p * 3 + 0] = dir_ij[e * 3 + 0];
    sdir[p * 3 + 1] = dir_ij[e * 3 + 1];
    sdir[p * 3 + 2] = dir_ij[e * 3 + 2];
}

// ---------------- fused edge kernel (R17 + CB=32 for 5 waves/SIMD) -------
// Grid (2500, 8). Block: 128 sorted edges x 32-col tile (96 W rows).
// acc[6][2] = 48 AGPR -> 5 waves/SIMD; LDS 21.5KB padded to 32KB ->
// 5 blocks/CU (20 waves/CU). Barrier-free main loop (fw2frag direct from
// L2, wave-private s_h); 2 barriers total (s_acc init/use, use/flush).
__global__ __launch_bounds__(256, 5) void k_edge(
    const int* __restrict__ perm, const float* __restrict__ rbf,
    const int* __restrict__ si, const int* __restrict__ sj,
    const float* __restrict__ sfc, const float* __restrict__ sdir,
    const unsigned short* __restrict__ fw1t2, const float* __restrict__ fb1,
    const unsigned short* __restrict__ fw2frag, const float* __restrict__ fb2,
    const unsigned short* __restrict__ ctx, const unsigned short* __restrict__ vbf,
    float* __restrict__ out_s, float* __restrict__ out_v) {
    __shared__ char sm[32768];           // padded: 160KB/32KB -> 5 blocks/CU
    char* s_h = sm;                      // [128 e][128B] h-hi (swz (e&7)<<4), 16KB
    float* s_acc = (float*)(sm + 16384); // [10 rows][4 arrays][32 cols] f32, 5KB

    int g = blockIdx.x;             // edge group — dispatch-fastest
    int ct = blockIdx.y;            // col tile (32 cols)

    int tid = threadIdx.x;
    int lane = tid & 63, w = tid >> 6;
    int l16 = lane & 15, g4 = lane >> 4;
    int e0 = g * 128;

    for (int k2 = tid; k2 < 1280; k2 += 256) s_acc[k2] = 0.f;

    int amin = si[e0], amax = si[e0 + 127];

    // ---- rbf fragments in registers (bf16-hi), per ef ----
    bf16x8 bfr_hi[2];
#pragma unroll
    for (int ef = 0; ef < 2; ++ef) {
        int pe = perm[e0 + 32 * w + 16 * ef + l16];
        const float* rr = rbf + (size_t)pe * N_RBF;
        float xx[8];
#pragma unroll
        for (int t = 0; t < 8; ++t) xx[t] = 0.f;
        if (g4 == 0) {
            float4 a = *(const float4*)(rr);
            float4 b = *(const float4*)(rr + 4);
            xx[0]=a.x; xx[1]=a.y; xx[2]=a.z; xx[3]=a.w;
            xx[4]=b.x; xx[5]=b.y; xx[6]=b.z; xx[7]=b.w;
        } else if (g4 == 1) {
            float4 a = *(const float4*)(rr + 8);
            float4 b = *(const float4*)(rr + 12);
            xx[0]=a.x; xx[1]=a.y; xx[2]=a.z; xx[3]=a.w;
            xx[4]=b.x; xx[5]=b.y; xx[6]=b.z; xx[7]=b.w;
        } else if (g4 == 2) {
            float4 a = *(const float4*)(rr + 16);
            xx[0]=a.x; xx[1]=a.y; xx[2]=a.z; xx[3]=a.w;
        }
        union { bf16x8 v; unsigned short s[8]; } uh;
#pragma unroll
        for (int t = 0; t < 8; ++t) uh.s[t] = f2bf(xx[t]);
        bfr_hi[ef] = uh.v;
    }

    f32x4 acc[6][2];
#pragma unroll
    for (int a = 0; a < 6; a++)
#pragma unroll
        for (int b = 0; b < 2; b++) acc[a][b] = (f32x4){0.f, 0.f, 0.f, 0.f};

    for (int q = 0; q < 8; ++q) {
        // (a) issue 6 coalesced W-frag loads (L2-resident table)
        bf16x8 awf[6];
#pragma unroll
        for (int nf = 0; nf < 6; ++nf)
            awf[nf] = *(const bf16x8*)(fw2frag +
                      ((size_t)(((ct * 8 + q) * 6 + nf) * 64) + lane) * 8);
        // (b) h chunk via 2-term split MFMA (fw1 hi+lo, rbf hi), hi-only
        //     store into wave-private s_h rows (no barrier needed)
#pragma unroll
        for (int cf = 0; cf < 2; ++cf) {
            const unsigned short* ar = fw1t2 + (size_t)(q * 32 + cf * 16 + l16) * 64;
            bf16x8 ahi = *(const bf16x8*)(ar + g4 * 8);
            bf16x8 alo = *(const bf16x8*)(ar + 32 + g4 * 8);
            int cbase = cf * 16 + g4 * 4;
            float4 b1 = *(const float4*)(fb1 + q * 32 + cbase);
#pragma unroll
            for (int ef = 0; ef < 2; ++ef) {
                f32x4 ha = (f32x4){0.f, 0.f, 0.f, 0.f};
                ha = MFMA16(ahi, bfr_hi[ef], ha, 0, 0, 0);
                ha = MFMA16(alo, bfr_hi[ef], ha, 0, 0, 0);
                float h0 = silu_f(ha[0] + b1.x);
                float h1 = silu_f(ha[1] + b1.y);
                float h2 = silu_f(ha[2] + b1.z);
                float h3 = silu_f(ha[3] + b1.w);
                uint2 pk;
                pk.x = (unsigned)f2bf(h0) | ((unsigned)f2bf(h1) << 16);
                pk.y = (unsigned)f2bf(h2) | ((unsigned)f2bf(h3) << 16);
                int e = 32 * w + 16 * ef + l16;
                *(uint2*)(s_h + e * 128 + ((2 * cbase) ^ ((e & 7) << 4))) = pk;
            }
        }
        // (c) main MFMA: 1-term, 6 n-frags x 2 e-frags
        bf16x8 bh[2];
#pragma unroll
        for (int ef = 0; ef < 2; ef++) {
            int e = 32 * w + 16 * ef + l16;
            bh[ef] = *(const bf16x8*)(s_h + e * 128 + ((16 * g4) ^ ((e & 7) << 4)));
        }
#pragma unroll
        for (int nf = 0; nf < 6; nf++)
#pragma unroll
            for (int ef = 0; ef < 2; ef++)
                acc[nf][ef] = MFMA16(awf[nf], bh[ef], acc[nf][ef], 0, 0, 0);
    }

    __syncthreads();   // s_acc zero-init visible before any ds_add

    // ---------------- epilogue ----------------
#pragma unroll
    for (int ef = 0; ef < 2; ++ef) {
        int E = e0 + 32 * w + 16 * ef + l16;
        int ai = si[E], aj = sj[E];
        float fc = sfc[E];
        float d0 = sdir[3 * E], d1 = sdir[3 * E + 1], d2 = sdir[3 * E + 2];
        int i1 = __shfl_down(ai, 1, 16), i2 = __shfl_down(ai, 2, 16);
        int i4 = __shfl_down(ai, 4, 16), i8 = __shfl_down(ai, 8, 16);
        int prevai = __shfl_up(ai, 1, 16);
        bool m1 = (l16 + 1 < 16) && (i1 == ai);
        bool m2 = (l16 + 2 < 16) && (i2 == ai);
        bool m4 = (l16 + 4 < 16) && (i4 == ai);
        bool m8 = (l16 + 8 < 16) && (i8 == ai);
        bool lead = (l16 == 0) || (prevai != ai);
        int row = ai - amin;
        // LDS accumulator row: 0-7 interior, 8 = amin, 9 = amax, -1 = fallback
        int accrow = (ai == amin) ? 8 : (ai == amax) ? 9 : (row <= 8 ? row - 1 : -1);
        const unsigned short* cj = ctx + (size_t)aj * H3;
        const unsigned short* vj = vbf + (size_t)aj * H3;
#pragma unroll
        for (int ci = 0; ci < 2; ++ci) {
            int Cb = ct * 32 + ci * 16 + g4 * 4;
            ushort4 c0u = *(const ushort4*)(cj + Cb);
            ushort4 c1u = *(const ushort4*)(cj + H + Cb);
            ushort4 c2u = *(const ushort4*)(cj + 2 * H + Cb);
            ushort4 u0u = *(const ushort4*)(vj + Cb);
            ushort4 u1u = *(const ushort4*)(vj + H + Cb);
            ushort4 u2u = *(const ushort4*)(vj + 2 * H + Cb);
            float4 b0 = *(const float4*)(fb2 + Cb);
            float4 b1 = *(const float4*)(fb2 + H + Cb);
            float4 b2 = *(const float4*)(fb2 + 2 * H + Cb);
            float c0f[4] = { bf2f(c0u.x), bf2f(c0u.y), bf2f(c0u.z), bf2f(c0u.w) };
            float c1f[4] = { bf2f(c1u.x), bf2f(c1u.y), bf2f(c1u.z), bf2f(c1u.w) };
            float c2f[4] = { bf2f(c2u.x), bf2f(c2u.y), bf2f(c2u.z), bf2f(c2u.w) };
            float u0f[4] = { bf2f(u0u.x), bf2f(u0u.y), bf2f(u0u.z), bf2f(u0u.w) };
            float u1f[4] = { bf2f(u1u.x), bf2f(u1u.y), bf2f(u1u.z), bf2f(u1u.w) };
            float u2f[4] = { bf2f(u2u.x), bf2f(u2u.y), bf2f(u2u.z), bf2f(u2u.w) };
            float vds[4], vv0[4], vv1[4], vv2[4];
#pragma unroll
            for (int r = 0; r < 4; ++r) {
                float w0 = acc[ci][ef][r]     + ((const float*)&b0)[r];
                float w1 = acc[2 + ci][ef][r] + ((const float*)&b1)[r];
                float w2 = acc[4 + ci][ef][r] + ((const float*)&b2)[r];
                float ds  = c0f[r] * w0 * fc;
                float dvs = c1f[r] * w1 * fc;
                float dvv = c2f[r] * w2 * fc;
                vds[r] = ds;
                vv0[r] = dvs * d0 + dvv * u0f[r];
                vv1[r] = dvs * d1 + dvv * u1f[r];
                vv2[r] = dvs * d2 + dvv * u2f[r];
            }
#pragma unroll
            for (int st = 0; st < 4; ++st) {
                int off = 1 << st;
                bool mm = (st == 0) ? m1 : (st == 1) ? m2 : (st == 2) ? m4 : m8;
#pragma unroll
                for (int r = 0; r < 4; ++r) {
                    float t0 = __shfl_down(vds[r], off, 16);
                    float t1 = __shfl_down(vv0[r], off, 16);
                    float t2 = __shfl_down(vv1[r], off, 16);
                    float t3 = __shfl_down(vv2[r], off, 16);
                    if (mm) { vds[r] += t0; vv0[r] += t1; vv1[r] += t2; vv2[r] += t3; }
                }
            }
            if (lead) {
                if (accrow >= 0) {
                    int base = accrow * 128;     // 4 arrays x 32 cols
                    int cl = ci * 16 + g4 * 4;
#pragma unroll
                    for (int r = 0; r < 4; ++r) {
                        atomicAdd(&s_acc[base + 0 * 32 + cl + r], vds[r]);
                        atomicAdd(&s_acc[base + 1 * 32 + cl + r], vv0[r]);
                        atomicAdd(&s_acc[base + 2 * 32 + cl + r], vv1[r]);
                        atomicAdd(&s_acc[base + 3 * 32 + cl + r], vv2[r]);
                    }
                } else {
#pragma unroll
                    for (int r = 0; r < 4; ++r) {
                        int C = Cb + r;
                        atomicAdd(&out_s[(size_t)ai * H + C], vds[r]);
                        atomicAdd(&out_v[(size_t)ai * H3 + C], vv0[r]);
                        atomicAdd(&out_v[(size_t)ai * H3 + H + C], vv1[r]);
                        atomicAdd(&out_v[(size_t)ai * H3 + 2 * H + C], vv2[r]);
                    }
                }
            }
        }
    }

    // ---- flush: interior rows plain RMW (sole writer); amin/amax atomic ----
    __syncthreads();
    for (int s5 = tid; s5 < 1280; s5 += 256) {
        float val = s_acc[s5];
        if (val != 0.f) {
            int cl = s5 & 31;
            int arr = (s5 >> 5) & 3;
            int rr = s5 >> 7;                 // 0..9
            int C = ct * 32 + cl;
            if (rr < 8) {
                int atom = amin + 1 + rr;     // exclusively owned
                if (arr == 0) {
                    float* p = &out_s[(size_t)atom * H + C];
                    *p = *p + val;
                } else {
                    float* p = &out_v[(size_t)atom * H3 + (arr - 1) * H + C];
                    *p = *p + val;
                }
            } else {
                int atom = (rr == 8) ? amin : amax;   // shared boundary
                if (arr == 0) atomicAdd(&out_s[(size_t)atom * H + C], val);
                else atomicAdd(&out_v[(size_t)atom * H3 + (arr - 1) * H + C], val);
            }
        }
    }
}

extern "C" void kernel_launch(void* const* d_in, const int* in_sizes, int n_in,
                              void* d_out, int out_size, void* d_ws, size_t ws_size,
                              hipStream_t stream) {
    const float* s      = (const float*)d_in[0];
    const float* v      = (const float*)d_in[1];
    const int*   idx_i  = (const int*)d_in[2];
    const int*   idx_j  = (const int*)d_in[3];
    const float* rbf    = (const float*)d_in[4];
    const float* f_cut  = (const float*)d_in[5];
    const float* dir_ij = (const float*)d_in[6];
    const float* inv    = (const float*)d_in[7];
    const float* ln_g   = (const float*)d_in[8];
    const float* ln_b   = (const float*)d_in[9];
    const float* cw1    = (const float*)d_in[10];
    const float* cb1    = (const float*)d_in[11];
    const float* cw2    = (const float*)d_in[12];
    const float* cb2    = (const float*)d_in[13];
    const float* fw1    = (const float*)d_in[14];
    const float* fb1    = (const float*)d_in[15];
    const float* fw2    = (const float*)d_in[16];
    const float* fb2    = (const float*)d_in[17];

    float* out_s = (float*)d_out;
    float* out_v = out_s + (size_t)N_ATOMS * H;

    // ---- ws layout (bytes), peak 46,628,864 ----
    char* wsb = (char*)d_ws;
    unsigned short* fw2frag  = (unsigned short*)(wsb + 0);          //    393,216
    unsigned short* fw1t2    = (unsigned short*)(wsb + 393216);     //     32,768
    int*            counts   = (int*)(wsb + 425984);                //     40,960
    int*            rowstart = (int*)(wsb + 466944);                //     40,960
    int*            cursor   = (int*)(wsb + 507904);                //     40,960
    unsigned short* vbf      = (unsigned short*)(wsb + 548864);     // 15,360,000 bf16
    unsigned short* ctx      = (unsigned short*)(wsb + 15908864);   // 15,360,000 bf16
    float*          sn       = (float*)(wsb + 31268864);            // 10,240,000
    unsigned short* ctx1     = (unsigned short*)(wsb + 41508864);   //  5,120,000 bf16
    // overlays of sn region (written only after gemm1 consumed sn):
    int*            perm     = (int*)(wsb + 31268864);              //  1,280,000
    int*            si       = (int*)(wsb + 32548864);
    int*            sj       = (int*)(wsb + 33828864);
    float*          sfc      = (float*)(wsb + 35108864);
    float*          sdir     = (float*)(wsb + 36388864);            //  3,840,000

    // init outputs with s, v (updates accumulated on top)
    hipMemcpyAsync(out_s, s, sizeof(float) * (size_t)N_ATOMS * H,
                   hipMemcpyDeviceToDevice, stream);
    hipMemcpyAsync(out_v, v, sizeof(float) * (size_t)N_ATOMS * 3 * H,
                   hipMemcpyDeviceToDevice, stream);
    hipMemsetAsync(counts, 0, 122880, stream);   // counts+rowstart+cursor

    // weight prep + v->bf16 + histogram
    k_prep_fw2frag<<<96, 256, 0, stream>>>(fw2, fw2frag);
    k_prep_fw1t2<<<1, 256, 0, stream>>>(fw1, fw1t2);
    k_prep_vbf<<<7500, 256, 0, stream>>>(v, vbf);     // 7.68M = 7500*1024
    k_hist<<<(N_EDGES + 255) / 256, 256, 0, stream>>>(idx_i, counts);
    k_scan<<<1, 256, 0, stream>>>(counts, rowstart);

    // context path (uses sn, then ctx1, then ctx)
    k_ln<<<N_ATOMS, 256, 0, stream>>>(s, ln_g, ln_b, sn);
    dim3 g1((N_ATOMS + 63) / 64, H / 64);
    k_gemm<1, 0, 1><<<g1, 256, 0, stream>>>(sn, cw1, cb1, ctx1, N_ATOMS, H, H);

    // fused scatter+gather (overlays sn, dead now)
    k_scatter<<<(N_EDGES + 255) / 256, 256, 0, stream>>>(
        idx_i, idx_j, f_cut, dir_ij, inv, rowstart, cursor,
        perm, si, sj, sfc, sdir);

    dim3 g2((N_ATOMS + 63) / 64, H3 / 64);
    k_gemm<0, 1, 1><<<g2, 256, 0, stream>>>(ctx1, cw2, cb2, ctx, N_ATOMS, H3, H);

    // fused edge GEMM + scatter — x = edge group (dispatch-fastest)
    dim3 ge(2500, 8);
    k_edge<<<ge, 256, 0, stream>>>(perm, rbf, si, sj, sfc, sdir, fw1t2, fb1,
                                   fw2frag, fb2, ctx, vbf, out_s, out_v);
}

// Round 19
// 886.122 us; speedup vs baseline: 1.3872x; 1.3872x over previous
//
#include <hip/hip_runtime.h>
#include <hip/hip_bf16.h>

#define N_ATOMS 10000
#define N_EDGES 320000
#define H 256
#define H3 768
#define N_RBF 20
#define LN_EPS 1e-5f

typedef __attribute__((ext_vector_type(8))) short bf16x8;
typedef __attribute__((ext_vector_type(4))) float f32x4;
#define MFMA16 __builtin_amdgcn_mfma_f32_16x16x32_bf16

__device__ __forceinline__ float silu_f(float x) { return x / (1.f + __expf(-x)); }

__device__ __forceinline__ unsigned short f2bf(float x) {
    union { float f; unsigned u; } v; v.f = x;
    unsigned r = v.u + 0x7fff + ((v.u >> 16) & 1);
    return (unsigned short)(r >> 16);
}
__device__ __forceinline__ float bf2f(unsigned short b) {
    union { unsigned u; float f; } v; v.u = ((unsigned)b) << 16; return v.f;
}

// ---------------- LayerNorm: one block (256 thr) per atom ----------------
__global__ __launch_bounds__(256) void k_ln(const float* __restrict__ s,
                                            const float* __restrict__ g,
                                            const float* __restrict__ b,
                                            float* __restrict__ sn) {
    int a = blockIdx.x, t = threadIdx.x;
    float x = s[(size_t)a * H + t];
    __shared__ float red[4];
    float v = x;
    for (int o = 32; o > 0; o >>= 1) v += __shfl_down(v, o);
    if ((t & 63) == 0) red[t >> 6] = v;
    __syncthreads();
    float mu = (red[0] + red[1] + red[2] + red[3]) * (1.f / H);
    float dx = x - mu;
    __syncthreads();
    v = dx * dx;
    for (int o = 32; o > 0; o >>= 1) v += __shfl_down(v, o);
    if ((t & 63) == 0) red[t >> 6] = v;
    __syncthreads();
    float var = (red[0] + red[1] + red[2] + red[3]) * (1.f / H);
    float rs = rsqrtf(var + LN_EPS);
    sn[(size_t)a * H + t] = dx * rs * g[t] + b[t];
}

// ---------------- fp32 tiled GEMM: C = [silu](A@B + bias) ----------------
template <int DO_SILU, int IN_BF16, int OUT_BF16>
__global__ __launch_bounds__(256) void k_gemm(const void* __restrict__ Av,
                                              const float* __restrict__ B,
                                              const float* __restrict__ bias,
                                              void* __restrict__ Cv,
                                              int M, int N, int K) {
    const int BM = 64, BN = 64, BK = 16;
    __shared__ float As[BK][BM + 1];
    __shared__ float Bs[BK][BN + 1];
    int tid = threadIdx.x;
    int m0 = blockIdx.x * BM, n0 = blockIdx.y * BN;
    int ty = tid >> 4, tx = tid & 15;
    float acc[4][4] = {};
    for (int k0 = 0; k0 < K; k0 += BK) {
        {
            int kk = tid & 15, mm = tid >> 4;
            for (int r = 0; r < 4; r++) {
                int m = mm + r * 16;
                int gm = m0 + m;
                float a = 0.f;
                if (gm < M) {
                    if (IN_BF16) a = bf2f(((const unsigned short*)Av)[(size_t)gm * K + k0 + kk]);
                    else         a = ((const float*)Av)[(size_t)gm * K + k0 + kk];
                }
                As[kk][m] = a;
            }
        }
        {
            int n = tid & 63, kk = tid >> 6;
            for (int r = 0; r < 4; r++) {
                int k = kk + r * 4;
                Bs[k][n] = B[(size_t)(k0 + k) * N + n0 + n];
            }
        }
        __syncthreads();
        for (int k = 0; k < BK; k++) {
            float a[4], bb[4];
            for (int i = 0; i < 4; i++) a[i] = As[k][ty * 4 + i];
            for (int j = 0; j < 4; j++) bb[j] = Bs[k][tx * 4 + j];
            for (int i = 0; i < 4; i++)
                for (int j = 0; j < 4; j++) acc[i][j] += a[i] * bb[j];
        }
        __syncthreads();
    }
    for (int i = 0; i < 4; i++) {
        int gm = m0 + ty * 4 + i;
        if (gm >= M) continue;
        for (int j = 0; j < 4; j++) {
            int gn = n0 + tx * 4 + j;
            float y = acc[i][j] + bias[gn];
            if (DO_SILU) y = silu_f(y);
            if (OUT_BF16) ((unsigned short*)Cv)[(size_t)gm * N + gn] = f2bf(y);
            else          ((float*)Cv)[(size_t)gm * N + gn] = y;
        }
    }
}

// ---------------- weight prep ----------------
// fw2frag: fragment-ordered bf16 table, record u = ((ct*8+q)*12+nf)*64+lane,
// 8 shorts per record: fw2[k0+j][n_glob], k0=q*32+(lane>>4)*8,
// n=nf*16+(lane&15), n_glob=(n>>6)*256+ct*64+(n&63). 393,216 B total.
__global__ __launch_bounds__(256) void k_prep_fw2frag(const float* __restrict__ fw2,
                                                      unsigned short* __restrict__ fw2frag) {
    int u = blockIdx.x * 256 + threadIdx.x;       // 0..24575
    int lane = u & 63;
    int rest = u >> 6;                            // 0..383
    int nf = rest % 12;
    int q = (rest / 12) % 8;
    int ct = rest / 96;
    int n = nf * 16 + (lane & 15);
    int n_glob = (n >> 6) * 256 + ct * 64 + (n & 63);
    int k0 = q * 32 + (lane >> 4) * 8;
    unsigned short rec[8];
#pragma unroll
    for (int j = 0; j < 8; ++j)
        rec[j] = f2bf(fw2[(size_t)(k0 + j) * H3 + n_glob]);
    ushort4* dst = (ushort4*)(fw2frag + (size_t)u * 8);
    dst[0] = make_ushort4(rec[0], rec[1], rec[2], rec[3]);
    dst[1] = make_ushort4(rec[4], rec[5], rec[6], rec[7]);
}
__global__ __launch_bounds__(256) void k_prep_fw1t2(const float* __restrict__ fw1,
                                                    unsigned short* __restrict__ fw1t2) {
    int c = threadIdx.x;
    for (int k = 0; k < 32; k++) {
        float wv = (k < N_RBF) ? fw1[k * H + c] : 0.f;
        unsigned short hi = f2bf(wv);
        unsigned short lo = f2bf(wv - bf2f(hi));
        fw1t2[c * 64 + k] = hi;
        fw1t2[c * 64 + 32 + k] = lo;
    }
}
// v (fp32, 7.68M elems) -> bf16 copy for the edge-kernel gathers
__global__ __launch_bounds__(256) void k_prep_vbf(const float* __restrict__ v,
                                                  unsigned short* __restrict__ vbf) {
    int i = blockIdx.x * 1024 + threadIdx.x * 4;
    float4 a = *(const float4*)(v + i);
    ushort4 o;
    o.x = f2bf(a.x); o.y = f2bf(a.y); o.z = f2bf(a.z); o.w = f2bf(a.w);
    *(ushort4*)(vbf + i) = o;
}

// ---------------- counting sort by idx_i ----------------
__global__ __launch_bounds__(256) void k_hist(const int* __restrict__ idx_i,
                                              int* __restrict__ counts) {
    int e = blockIdx.x * 256 + threadIdx.x;
    if (e < N_EDGES) atomicAdd(&counts[idx_i[e]], 1);
}
__global__ __launch_bounds__(256) void k_scan(const int* __restrict__ counts,
                                              int* __restrict__ rowstart) {
    __shared__ int part[257];
    int t = threadIdx.x;
    const int PER = 40;
    int s = 0;
    for (int r = 0; r < PER; ++r) { int i = t * PER + r; if (i < N_ATOMS) s += counts[i]; }
    part[t + 1] = s;
    if (t == 0) part[0] = 0;
    __syncthreads();
    for (int off = 1; off < 256; off <<= 1) {
        int v = (t + 1 > off) ? part[t + 1 - off] : 0;
        __syncthreads();
        part[t + 1] += v;
        __syncthreads();
    }
    int run = part[t];
    for (int r = 0; r < PER; ++r) {
        int i = t * PER + r;
        if (i < N_ATOMS) { rowstart[i] = run; run += counts[i]; }
    }
    if (t == 255) rowstart[N_ATOMS] = run;
}
// scatter with fused gather: one pass builds perm + sorted edge metadata
__global__ __launch_bounds__(256) void k_scatter(const int* __restrict__ idx_i,
                                                 const int* __restrict__ idx_j,
                                                 const float* __restrict__ f_cut,
                                                 const float* __restrict__ dir_ij,
                                                 const float* __restrict__ inv_ptr,
                                                 const int* __restrict__ rowstart,
                                                 int* __restrict__ cursor,
                                                 int* __restrict__ perm,
                                                 int* __restrict__ si, int* __restrict__ sj,
                                                 float* __restrict__ sfc,
                                                 float* __restrict__ sdir) {
    int e = blockIdx.x * 256 + threadIdx.x;
    if (e >= N_EDGES) return;
    int i = idx_i[e];
    int p = rowstart[i] + atomicAdd(&cursor[i], 1);
    perm[p] = e;
    si[p] = i;
    sj[p] = idx_j[e];
    sfc[p] = f_cut[e] * inv_ptr[0];
    sdir[p * 3 + 0] = dir_ij[e * 3 + 0];
    sdir[p * 3 + 1] = dir_ij[e * 3 + 1];
    sdir[p * 3 + 2] = dir_ij[e * 3 + 2];
}

// ---------------- fused edge kernel (R17: barrier-free main loop) --------
// Grid (2500, 4). Block: 128 sorted edges x 64-col tile (192 W rows).
// W fragments read directly from the L2-resident fw2frag table (coalesced
// 1KB per wave-load) -> NO s_w staging, NO per-q barriers. s_h is
// wave-private. Only 2 barriers/block (s_acc init->use, use->flush).
// LDS padded to 44KB to pin 3 blocks/CU (L2-thrash guard: R8/R15/R18 all
// showed >=4 concurrent blocks/CU explodes FETCH/WRITE via L2 capacity).
__global__ __launch_bounds__(256, 3) void k_edge(
    const int* __restrict__ perm, const float* __restrict__ rbf,
    const int* __restrict__ si, const int* __restrict__ sj,
    const float* __restrict__ sfc, const float* __restrict__ sdir,
    const unsigned short* __restrict__ fw1t2, const float* __restrict__ fb1,
    const unsigned short* __restrict__ fw2frag, const float* __restrict__ fb2,
    const unsigned short* __restrict__ ctx, const unsigned short* __restrict__ vbf,
    float* __restrict__ out_s, float* __restrict__ out_v) {
    __shared__ char sm[44032];           // padded: 160KB/43KB -> 3 blocks/CU
    char* s_h = sm;                      // [128 e][128B] h-hi (swz (e&7)<<4), 16KB
    float* s_acc = (float*)(sm + 16384); // [10 rows][4 arrays][64 cols] f32, 10KB

    int g = blockIdx.x;             // edge group — dispatch-fastest
    int ct = blockIdx.y;            // col tile

    int tid = threadIdx.x;
    int lane = tid & 63, w = tid >> 6;
    int l16 = lane & 15, g4 = lane >> 4;
    int e0 = g * 128;

    for (int k2 = tid; k2 < 2560; k2 += 256) s_acc[k2] = 0.f;

    int amin = si[e0], amax = si[e0 + 127];

    // ---- rbf fragments in registers (bf16-hi), per ef ----
    bf16x8 bfr_hi[2];
#pragma unroll
    for (int ef = 0; ef < 2; ++ef) {
        int pe = perm[e0 + 32 * w + 16 * ef + l16];
        const float* rr = rbf + (size_t)pe * N_RBF;
        float xx[8];
#pragma unroll
        for (int t = 0; t < 8; ++t) xx[t] = 0.f;
        if (g4 == 0) {
            float4 a = *(const float4*)(rr);
            float4 b = *(const float4*)(rr + 4);
            xx[0]=a.x; xx[1]=a.y; xx[2]=a.z; xx[3]=a.w;
            xx[4]=b.x; xx[5]=b.y; xx[6]=b.z; xx[7]=b.w;
        } else if (g4 == 1) {
            float4 a = *(const float4*)(rr + 8);
            float4 b = *(const float4*)(rr + 12);
            xx[0]=a.x; xx[1]=a.y; xx[2]=a.z; xx[3]=a.w;
            xx[4]=b.x; xx[5]=b.y; xx[6]=b.z; xx[7]=b.w;
        } else if (g4 == 2) {
            float4 a = *(const float4*)(rr + 16);
            xx[0]=a.x; xx[1]=a.y; xx[2]=a.z; xx[3]=a.w;
        }
        union { bf16x8 v; unsigned short s[8]; } uh;
#pragma unroll
        for (int t = 0; t < 8; ++t) uh.s[t] = f2bf(xx[t]);
        bfr_hi[ef] = uh.v;
    }

    f32x4 acc[12][2];
#pragma unroll
    for (int a = 0; a < 12; a++)
#pragma unroll
        for (int b = 0; b < 2; b++) acc[a][b] = (f32x4){0.f, 0.f, 0.f, 0.f};

    for (int q = 0; q < 8; ++q) {
        // (a) issue 12 coalesced W-frag loads (L2-resident table)
        bf16x8 awf[12];
#pragma unroll
        for (int nf = 0; nf < 12; ++nf)
            awf[nf] = *(const bf16x8*)(fw2frag +
                      ((size_t)(((ct * 8 + q) * 12 + nf) * 64) + lane) * 8);
        // (b) h chunk via 2-term split MFMA (fw1 hi+lo, rbf hi), hi-only
        //     store into wave-private s_h rows (no barrier needed)
#pragma unroll
        for (int cf = 0; cf < 2; ++cf) {
            const unsigned short* ar = fw1t2 + (size_t)(q * 32 + cf * 16 + l16) * 64;
            bf16x8 ahi = *(const bf16x8*)(ar + g4 * 8);
            bf16x8 alo = *(const bf16x8*)(ar + 32 + g4 * 8);
            int cbase = cf * 16 + g4 * 4;
            float4 b1 = *(const float4*)(fb1 + q * 32 + cbase);
#pragma unroll
            for (int ef = 0; ef < 2; ++ef) {
                f32x4 ha = (f32x4){0.f, 0.f, 0.f, 0.f};
                ha = MFMA16(ahi, bfr_hi[ef], ha, 0, 0, 0);
                ha = MFMA16(alo, bfr_hi[ef], ha, 0, 0, 0);
                float h0 = silu_f(ha[0] + b1.x);
                float h1 = silu_f(ha[1] + b1.y);
                float h2 = silu_f(ha[2] + b1.z);
                float h3 = silu_f(ha[3] + b1.w);
                uint2 pk;
                pk.x = (unsigned)f2bf(h0) | ((unsigned)f2bf(h1) << 16);
                pk.y = (unsigned)f2bf(h2) | ((unsigned)f2bf(h3) << 16);
                int e = 32 * w + 16 * ef + l16;
                *(uint2*)(s_h + e * 128 + ((2 * cbase) ^ ((e & 7) << 4))) = pk;
            }
        }
        // (c) main MFMA: 1-term, 12 n-frags x 2 e-frags
        bf16x8 bh[2];
#pragma unroll
        for (int ef = 0; ef < 2; ef++) {
            int e = 32 * w + 16 * ef + l16;
            bh[ef] = *(const bf16x8*)(s_h + e * 128 + ((16 * g4) ^ ((e & 7) << 4)));
        }
#pragma unroll
        for (int nf = 0; nf < 12; nf++)
#pragma unroll
            for (int ef = 0; ef < 2; ef++)
                acc[nf][ef] = MFMA16(awf[nf], bh[ef], acc[nf][ef], 0, 0, 0);
    }

    __syncthreads();   // s_acc zero-init visible before any ds_add

    // ---------------- epilogue ----------------
#pragma unroll
    for (int ef = 0; ef < 2; ++ef) {
        int E = e0 + 32 * w + 16 * ef + l16;
        int ai = si[E], aj = sj[E];
        float fc = sfc[E];
        float d0 = sdir[3 * E], d1 = sdir[3 * E + 1], d2 = sdir[3 * E + 2];
        int i1 = __shfl_down(ai, 1, 16), i2 = __shfl_down(ai, 2, 16);
        int i4 = __shfl_down(ai, 4, 16), i8 = __shfl_down(ai, 8, 16);
        int prevai = __shfl_up(ai, 1, 16);
        bool m1 = (l16 + 1 < 16) && (i1 == ai);
        bool m2 = (l16 + 2 < 16) && (i2 == ai);
        bool m4 = (l16 + 4 < 16) && (i4 == ai);
        bool m8 = (l16 + 8 < 16) && (i8 == ai);
        bool lead = (l16 == 0) || (prevai != ai);
        int row = ai - amin;
        // LDS accumulator row: 0-7 interior, 8 = amin, 9 = amax, -1 = fallback
        int accrow = (ai == amin) ? 8 : (ai == amax) ? 9 : (row <= 8 ? row - 1 : -1);
        const unsigned short* cj = ctx + (size_t)aj * H3;
        const unsigned short* vj = vbf + (size_t)aj * H3;
#pragma unroll
        for (int ci = 0; ci < 4; ++ci) {
            int Cb = ct * 64 + ci * 16 + g4 * 4;
            ushort4 c0u = *(const ushort4*)(cj + Cb);
            ushort4 c1u = *(const ushort4*)(cj + H + Cb);
            ushort4 c2u = *(const ushort4*)(cj + 2 * H + Cb);
            ushort4 u0u = *(const ushort4*)(vj + Cb);
            ushort4 u1u = *(const ushort4*)(vj + H + Cb);
            ushort4 u2u = *(const ushort4*)(vj + 2 * H + Cb);
            float4 b0 = *(const float4*)(fb2 + Cb);
            float4 b1 = *(const float4*)(fb2 + H + Cb);
            float4 b2 = *(const float4*)(fb2 + 2 * H + Cb);
            float c0f[4] = { bf2f(c0u.x), bf2f(c0u.y), bf2f(c0u.z), bf2f(c0u.w) };
            float c1f[4] = { bf2f(c1u.x), bf2f(c1u.y), bf2f(c1u.z), bf2f(c1u.w) };
            float c2f[4] = { bf2f(c2u.x), bf2f(c2u.y), bf2f(c2u.z), bf2f(c2u.w) };
            float u0f[4] = { bf2f(u0u.x), bf2f(u0u.y), bf2f(u0u.z), bf2f(u0u.w) };
            float u1f[4] = { bf2f(u1u.x), bf2f(u1u.y), bf2f(u1u.z), bf2f(u1u.w) };
            float u2f[4] = { bf2f(u2u.x), bf2f(u2u.y), bf2f(u2u.z), bf2f(u2u.w) };
            float vds[4], vv0[4], vv1[4], vv2[4];
#pragma unroll
            for (int r = 0; r < 4; ++r) {
                float w0 = acc[ci][ef][r]     + ((const float*)&b0)[r];
                float w1 = acc[4 + ci][ef][r] + ((const float*)&b1)[r];
                float w2 = acc[8 + ci][ef][r] + ((const float*)&b2)[r];
                float ds  = c0f[r] * w0 * fc;
                float dvs = c1f[r] * w1 * fc;
                float dvv = c2f[r] * w2 * fc;
                vds[r] = ds;
                vv0[r] = dvs * d0 + dvv * u0f[r];
                vv1[r] = dvs * d1 + dvv * u1f[r];
                vv2[r] = dvs * d2 + dvv * u2f[r];
            }
#pragma unroll
            for (int st = 0; st < 4; ++st) {
                int off = 1 << st;
                bool mm = (st == 0) ? m1 : (st == 1) ? m2 : (st == 2) ? m4 : m8;
#pragma unroll
                for (int r = 0; r < 4; ++r) {
                    float t0 = __shfl_down(vds[r], off, 16);
                    float t1 = __shfl_down(vv0[r], off, 16);
                    float t2 = __shfl_down(vv1[r], off, 16);
                    float t3 = __shfl_down(vv2[r], off, 16);
                    if (mm) { vds[r] += t0; vv0[r] += t1; vv1[r] += t2; vv2[r] += t3; }
                }
            }
            if (lead) {
                if (accrow >= 0) {
                    int base = accrow * 256;     // 4 arrays x 64 cols
                    int cl = ci * 16 + g4 * 4;
#pragma unroll
                    for (int r = 0; r < 4; ++r) {
                        atomicAdd(&s_acc[base + 0 * 64 + cl + r], vds[r]);
                        atomicAdd(&s_acc[base + 1 * 64 + cl + r], vv0[r]);
                        atomicAdd(&s_acc[base + 2 * 64 + cl + r], vv1[r]);
                        atomicAdd(&s_acc[base + 3 * 64 + cl + r], vv2[r]);
                    }
                } else {
#pragma unroll
                    for (int r = 0; r < 4; ++r) {
                        int C = Cb + r;
                        atomicAdd(&out_s[(size_t)ai * H + C], vds[r]);
                        atomicAdd(&out_v[(size_t)ai * H3 + C], vv0[r]);
                        atomicAdd(&out_v[(size_t)ai * H3 + H + C], vv1[r]);
                        atomicAdd(&out_v[(size_t)ai * H3 + 2 * H + C], vv2[r]);
                    }
                }
            }
        }
    }

    // ---- flush: interior rows plain RMW (sole writer); amin/amax atomic ----
    __syncthreads();
    for (int s5 = tid; s5 < 2560; s5 += 256) {
        float val = s_acc[s5];
        if (val != 0.f) {
            int cl = s5 & 63;
            int arr = (s5 >> 6) & 3;
            int rr = s5 >> 8;                 // 0..9
            int C = ct * 64 + cl;
            if (rr < 8) {
                int atom = amin + 1 + rr;     // exclusively owned
                if (arr == 0) {
                    float* p = &out_s[(size_t)atom * H + C];
                    *p = *p + val;
                } else {
                    float* p = &out_v[(size_t)atom * H3 + (arr - 1) * H + C];
                    *p = *p + val;
                }
            } else {
                int atom = (rr == 8) ? amin : amax;   // shared boundary
                if (arr == 0) atomicAdd(&out_s[(size_t)atom * H + C], val);
                else atomicAdd(&out_v[(size_t)atom * H3 + (arr - 1) * H + C], val);
            }
        }
    }
}

extern "C" void kernel_launch(void* const* d_in, const int* in_sizes, int n_in,
                              void* d_out, int out_size, void* d_ws, size_t ws_size,
                              hipStream_t stream) {
    const float* s      = (const float*)d_in[0];
    const float* v      = (const float*)d_in[1];
    const int*   idx_i  = (const int*)d_in[2];
    const int*   idx_j  = (const int*)d_in[3];
    const float* rbf    = (const float*)d_in[4];
    const float* f_cut  = (const float*)d_in[5];
    const float* dir_ij = (const float*)d_in[6];
    const float* inv    = (const float*)d_in[7];
    const float* ln_g   = (const float*)d_in[8];
    const float* ln_b   = (const float*)d_in[9];
    const float* cw1    = (const float*)d_in[10];
    const float* cb1    = (const float*)d_in[11];
    const float* cw2    = (const float*)d_in[12];
    const float* cb2    = (const float*)d_in[13];
    const float* fw1    = (const float*)d_in[14];
    const float* fb1    = (const float*)d_in[15];
    const float* fw2    = (const float*)d_in[16];
    const float* fb2    = (const float*)d_in[17];

    float* out_s = (float*)d_out;
    float* out_v = out_s + (size_t)N_ATOMS * H;

    // ---- ws layout (bytes), peak 46,628,864 ----
    char* wsb = (char*)d_ws;
    unsigned short* fw2frag  = (unsigned short*)(wsb + 0);          //    393,216
    unsigned short* fw1t2    = (unsigned short*)(wsb + 393216);     //     32,768
    int*            counts   = (int*)(wsb + 425984);                //     40,960
    int*            rowstart = (int*)(wsb + 466944);                //     40,960
    int*            cursor   = (int*)(wsb + 507904);                //     40,960
    unsigned short* vbf      = (unsigned short*)(wsb + 548864);     // 15,360,000 bf16
    unsigned short* ctx      = (unsigned short*)(wsb + 15908864);   // 15,360,000 bf16
    float*          sn       = (float*)(wsb + 31268864);            // 10,240,000
    unsigned short* ctx1     = (unsigned short*)(wsb + 41508864);   //  5,120,000 bf16
    // overlays of sn region (written only after gemm1 consumed sn):
    int*            perm     = (int*)(wsb + 31268864);              //  1,280,000
    int*            si       = (int*)(wsb + 32548864);
    int*            sj       = (int*)(wsb + 33828864);
    float*          sfc      = (float*)(wsb + 35108864);
    float*          sdir     = (float*)(wsb + 36388864);            //  3,840,000

    // init outputs with s, v (updates accumulated on top)
    hipMemcpyAsync(out_s, s, sizeof(float) * (size_t)N_ATOMS * H,
                   hipMemcpyDeviceToDevice, stream);
    hipMemcpyAsync(out_v, v, sizeof(float) * (size_t)N_ATOMS * 3 * H,
                   hipMemcpyDeviceToDevice, stream);
    hipMemsetAsync(counts, 0, 122880, stream);   // counts+rowstart+cursor

    // weight prep + v->bf16 + histogram
    k_prep_fw2frag<<<96, 256, 0, stream>>>(fw2, fw2frag);
    k_prep_fw1t2<<<1, 256, 0, stream>>>(fw1, fw1t2);
    k_prep_vbf<<<7500, 256, 0, stream>>>(v, vbf);     // 7.68M = 7500*1024
    k_hist<<<(N_EDGES + 255) / 256, 256, 0, stream>>>(idx_i, counts);
    k_scan<<<1, 256, 0, stream>>>(counts, rowstart);

    // context path (uses sn, then ctx1, then ctx)
    k_ln<<<N_ATOMS, 256, 0, stream>>>(s, ln_g, ln_b, sn);
    dim3 g1((N_ATOMS + 63) / 64, H / 64);
    k_gemm<1, 0, 1><<<g1, 256, 0, stream>>>(sn, cw1, cb1, ctx1, N_ATOMS, H, H);

    // fused scatter+gather (overlays sn, dead now)
    k_scatter<<<(N_EDGES + 255) / 256, 256, 0, stream>>>(
        idx_i, idx_j, f_cut, dir_ij, inv, rowstart, cursor,
        perm, si, sj, sfc, sdir);

    dim3 g2((N_ATOMS + 63) / 64, H3 / 64);
    k_gemm<0, 1, 1><<<g2, 256, 0, stream>>>(ctx1, cw2, cb2, ctx, N_ATOMS, H3, H);

    // fused edge GEMM + scatter — x = edge group (dispatch-fastest)
    dim3 ge(2500, 4);
    k_edge<<<ge, 256, 0, stream>>>(perm, rbf, si, sj, sfc, sdir, fw1t2, fb1,
                                   fw2frag, fb2, ctx, vbf, out_s, out_v);
}

// Round 20
// 826.079 us; speedup vs baseline: 1.4880x; 1.0727x over previous
//
#include <hip/hip_runtime.h>
#include <hip/hip_bf16.h>

#define N_ATOMS 10000
#define N_EDGES 320000
#define H 256
#define H3 768
#define N_RBF 20
#define LN_EPS 1e-5f

typedef __attribute__((ext_vector_type(8))) short bf16x8;
typedef __attribute__((ext_vector_type(4))) float f32x4;
#define MFMA16 __builtin_amdgcn_mfma_f32_16x16x32_bf16

__device__ __forceinline__ float silu_f(float x) { return x / (1.f + __expf(-x)); }

__device__ __forceinline__ unsigned short f2bf(float x) {
    union { float f; unsigned u; } v; v.f = x;
    unsigned r = v.u + 0x7fff + ((v.u >> 16) & 1);
    return (unsigned short)(r >> 16);
}
__device__ __forceinline__ float bf2f(unsigned short b) {
    union { unsigned u; float f; } v; v.u = ((unsigned)b) << 16; return v.f;
}

// ---------------- LayerNorm: one block (256 thr) per atom ----------------
__global__ __launch_bounds__(256) void k_ln(const float* __restrict__ s,
                                            const float* __restrict__ g,
                                            const float* __restrict__ b,
                                            float* __restrict__ sn) {
    int a = blockIdx.x, t = threadIdx.x;
    float x = s[(size_t)a * H + t];
    __shared__ float red[4];
    float v = x;
    for (int o = 32; o > 0; o >>= 1) v += __shfl_down(v, o);
    if ((t & 63) == 0) red[t >> 6] = v;
    __syncthreads();
    float mu = (red[0] + red[1] + red[2] + red[3]) * (1.f / H);
    float dx = x - mu;
    __syncthreads();
    v = dx * dx;
    for (int o = 32; o > 0; o >>= 1) v += __shfl_down(v, o);
    if ((t & 63) == 0) red[t >> 6] = v;
    __syncthreads();
    float var = (red[0] + red[1] + red[2] + red[3]) * (1.f / H);
    float rs = rsqrtf(var + LN_EPS);
    sn[(size_t)a * H + t] = dx * rs * g[t] + b[t];
}

// ---------------- fp32 tiled GEMM: C = [silu](A@B + bias) ----------------
// (still used for gemm1: sn @ cw1 -> ctx1 bf16)
template <int DO_SILU, int IN_BF16, int OUT_BF16>
__global__ __launch_bounds__(256) void k_gemm(const void* __restrict__ Av,
                                              const float* __restrict__ B,
                                              const float* __restrict__ bias,
                                              void* __restrict__ Cv,
                                              int M, int N, int K) {
    const int BM = 64, BN = 64, BK = 16;
    __shared__ float As[BK][BM + 1];
    __shared__ float Bs[BK][BN + 1];
    int tid = threadIdx.x;
    int m0 = blockIdx.x * BM, n0 = blockIdx.y * BN;
    int ty = tid >> 4, tx = tid & 15;
    float acc[4][4] = {};
    for (int k0 = 0; k0 < K; k0 += BK) {
        {
            int kk = tid & 15, mm = tid >> 4;
            for (int r = 0; r < 4; r++) {
                int m = mm + r * 16;
                int gm = m0 + m;
                float a = 0.f;
                if (gm < M) {
                    if (IN_BF16) a = bf2f(((const unsigned short*)Av)[(size_t)gm * K + k0 + kk]);
                    else         a = ((const float*)Av)[(size_t)gm * K + k0 + kk];
                }
                As[kk][m] = a;
            }
        }
        {
            int n = tid & 63, kk = tid >> 6;
            for (int r = 0; r < 4; r++) {
                int k = kk + r * 4;
                Bs[k][n] = B[(size_t)(k0 + k) * N + n0 + n];
            }
        }
        __syncthreads();
        for (int k = 0; k < BK; k++) {
            float a[4], bb[4];
            for (int i = 0; i < 4; i++) a[i] = As[k][ty * 4 + i];
            for (int j = 0; j < 4; j++) bb[j] = Bs[k][tx * 4 + j];
            for (int i = 0; i < 4; i++)
                for (int j = 0; j < 4; j++) acc[i][j] += a[i] * bb[j];
        }
        __syncthreads();
    }
    for (int i = 0; i < 4; i++) {
        int gm = m0 + ty * 4 + i;
        if (gm >= M) continue;
        for (int j = 0; j < 4; j++) {
            int gn = n0 + tx * 4 + j;
            float y = acc[i][j] + bias[gn];
            if (DO_SILU) y = silu_f(y);
            if (OUT_BF16) ((unsigned short*)Cv)[(size_t)gm * N + gn] = f2bf(y);
            else          ((float*)Cv)[(size_t)gm * N + gn] = y;
        }
    }
}

// ---------------- weight prep ----------------
// fw2frag: fragment-ordered bf16 table, record u = ((ct*8+q)*12+nf)*64+lane,
// 8 shorts per record: fw2[k0+j][n_glob], k0=q*32+(lane>>4)*8,
// n=nf*16+(lane&15), n_glob=(n>>6)*256+ct*64+(n&63). 393,216 B total.
__global__ __launch_bounds__(256) void k_prep_fw2frag(const float* __restrict__ fw2,
                                                      unsigned short* __restrict__ fw2frag) {
    int u = blockIdx.x * 256 + threadIdx.x;       // 0..24575
    int lane = u & 63;
    int rest = u >> 6;                            // 0..383
    int nf = rest % 12;
    int q = (rest / 12) % 8;
    int ct = rest / 96;
    int n = nf * 16 + (lane & 15);
    int n_glob = (n >> 6) * 256 + ct * 64 + (n & 63);
    int k0 = q * 32 + (lane >> 4) * 8;
    unsigned short rec[8];
#pragma unroll
    for (int j = 0; j < 8; ++j)
        rec[j] = f2bf(fw2[(size_t)(k0 + j) * H3 + n_glob]);
    ushort4* dst = (ushort4*)(fw2frag + (size_t)u * 8);
    dst[0] = make_ushort4(rec[0], rec[1], rec[2], rec[3]);
    dst[1] = make_ushort4(rec[4], rec[5], rec[6], rec[7]);
}
// cw2frag2: fragment-ordered hi|lo split tables for gemm2 (ctx1 @ cw2).
// record u = ((ct*8+q)*6+nf)*64+lane; n_glob = ct*96 + nf*16 + (lane&15);
// k0 = q*32 + (lane>>4)*8. hi at u*8, lo at 196608 + u*8. 786,432 B total.
__global__ __launch_bounds__(256) void k_prep_cw2frag(const float* __restrict__ cw2,
                                                      unsigned short* __restrict__ t) {
    int u = blockIdx.x * 256 + threadIdx.x;       // 0..24575
    int lane = u & 63;
    int rest = u >> 6;                            // 0..383
    int nf = rest % 6;
    int q = (rest / 6) % 8;
    int ct = rest / 48;
    int n_glob = ct * 96 + nf * 16 + (lane & 15);
    int k0 = q * 32 + (lane >> 4) * 8;
    unsigned short rh[8], rl[8];
#pragma unroll
    for (int j = 0; j < 8; ++j) {
        float wv = cw2[(size_t)(k0 + j) * H3 + n_glob];
        rh[j] = f2bf(wv);
        rl[j] = f2bf(wv - bf2f(rh[j]));
    }
    ushort4* dh = (ushort4*)(t + (size_t)u * 8);
    dh[0] = make_ushort4(rh[0], rh[1], rh[2], rh[3]);
    dh[1] = make_ushort4(rh[4], rh[5], rh[6], rh[7]);
    ushort4* dl = (ushort4*)(t + 196608 + (size_t)u * 8);
    dl[0] = make_ushort4(rl[0], rl[1], rl[2], rl[3]);
    dl[1] = make_ushort4(rl[4], rl[5], rl[6], rl[7]);
}
__global__ __launch_bounds__(256) void k_prep_fw1t2(const float* __restrict__ fw1,
                                                    unsigned short* __restrict__ fw1t2) {
    int c = threadIdx.x;
    for (int k = 0; k < 32; k++) {
        float wv = (k < N_RBF) ? fw1[k * H + c] : 0.f;
        unsigned short hi = f2bf(wv);
        unsigned short lo = f2bf(wv - bf2f(hi));
        fw1t2[c * 64 + k] = hi;
        fw1t2[c * 64 + 32 + k] = lo;
    }
}
// v (fp32, 7.68M elems) -> bf16 copy for the edge-kernel gathers
__global__ __launch_bounds__(256) void k_prep_vbf(const float* __restrict__ v,
                                                  unsigned short* __restrict__ vbf) {
    int i = blockIdx.x * 1024 + threadIdx.x * 4;
    float4 a = *(const float4*)(v + i);
    ushort4 o;
    o.x = f2bf(a.x); o.y = f2bf(a.y); o.z = f2bf(a.z); o.w = f2bf(a.w);
    *(ushort4*)(vbf + i) = o;
}

// ---------------- gemm2 via MFMA: ctx = ctx1 @ cw2 + cb2 (bf16 out) ------
// Barrier-free, LDS-free. Grid (157, 8): 64 atoms x 96 cols per block.
// Wave w owns 16 atoms; per q: 1 ctx1 B-frag + 6x2 cw2 A-frags (hi+lo,
// fp32-grade) -> 12 MFMA. D layout: col=l16=atom, row=g4*4+r=n-in-frag.
__global__ __launch_bounds__(256) void k_gemm2_mfma(
    const unsigned short* __restrict__ ctx1,      // [10000][256] bf16
    const unsigned short* __restrict__ cw2frag2,  // hi|lo frag tables
    const float* __restrict__ cb2,
    unsigned short* __restrict__ ctx) {           // [10000][768] bf16
    int ct = blockIdx.y;
    int tid = threadIdx.x;
    int lane = tid & 63, w = tid >> 6;
    int l16 = lane & 15, g4 = lane >> 4;
    int m = blockIdx.x * 64 + w * 16 + l16;
    int mc = (m < N_ATOMS) ? m : (N_ATOMS - 1);   // clamp: garbage only
                                                  // affects unstored cols
    f32x4 acc[6];
#pragma unroll
    for (int a = 0; a < 6; ++a) acc[a] = (f32x4){0.f, 0.f, 0.f, 0.f};

    for (int q = 0; q < 8; ++q) {
        bf16x8 bm = *(const bf16x8*)(ctx1 + (size_t)mc * 256 + q * 32 + g4 * 8);
#pragma unroll
        for (int nf = 0; nf < 6; ++nf) {
            size_t base = ((size_t)((ct * 8 + q) * 6 + nf) * 64 + lane) * 8;
            bf16x8 ahi = *(const bf16x8*)(cw2frag2 + base);
            bf16x8 alo = *(const bf16x8*)(cw2frag2 + 196608 + base);
            acc[nf] = MFMA16(ahi, bm, acc[nf], 0, 0, 0);
            acc[nf] = MFMA16(alo, bm, acc[nf], 0, 0, 0);
        }
    }
    if (m < N_ATOMS) {
#pragma unroll
        for (int nf = 0; nf < 6; ++nf) {
            int nb = ct * 96 + nf * 16 + g4 * 4;
            float4 bb = *(const float4*)(cb2 + nb);
            ushort4 o;
            o.x = f2bf(acc[nf][0] + bb.x);
            o.y = f2bf(acc[nf][1] + bb.y);
            o.z = f2bf(acc[nf][2] + bb.z);
            o.w = f2bf(acc[nf][3] + bb.w);
            *(ushort4*)(ctx + (size_t)m * H3 + nb) = o;
        }
    }
}

// ---------------- counting sort by idx_i ----------------
__global__ __launch_bounds__(256) void k_hist(const int* __restrict__ idx_i,
                                              int* __restrict__ counts) {
    int e = blockIdx.x * 256 + threadIdx.x;
    if (e < N_EDGES) atomicAdd(&counts[idx_i[e]], 1);
}
__global__ __launch_bounds__(256) void k_scan(const int* __restrict__ counts,
                                              int* __restrict__ rowstart) {
    __shared__ int part[257];
    int t = threadIdx.x;
    const int PER = 40;
    int s = 0;
    for (int r = 0; r < PER; ++r) { int i = t * PER + r; if (i < N_ATOMS) s += counts[i]; }
    part[t + 1] = s;
    if (t == 0) part[0] = 0;
    __syncthreads();
    for (int off = 1; off < 256; off <<= 1) {
        int v = (t + 1 > off) ? part[t + 1 - off] : 0;
        __syncthreads();
        part[t + 1] += v;
        __syncthreads();
    }
    int run = part[t];
    for (int r = 0; r < PER; ++r) {
        int i = t * PER + r;
        if (i < N_ATOMS) { rowstart[i] = run; run += counts[i]; }
    }
    if (t == 255) rowstart[N_ATOMS] = run;
}
// scatter with fused gather: one pass builds perm + sorted edge metadata
__global__ __launch_bounds__(256) void k_scatter(const int* __restrict__ idx_i,
                                                 const int* __restrict__ idx_j,
                                                 const float* __restrict__ f_cut,
                                                 const float* __restrict__ dir_ij,
                                                 const float* __restrict__ inv_ptr,
                                                 const int* __restrict__ rowstart,
                                                 int* __restrict__ cursor,
                                                 int* __restrict__ perm,
                                                 int* __restrict__ si, int* __restrict__ sj,
                                                 float* __restrict__ sfc,
                                                 float* __restrict__ sdir) {
    int e = blockIdx.x * 256 + threadIdx.x;
    if (e >= N_EDGES) return;
    int i = idx_i[e];
    int p = rowstart[i] + atomicAdd(&cursor[i], 1);
    perm[p] = e;
    si[p] = i;
    sj[p] = idx_j[e];
    sfc[p] = f_cut[e] * inv_ptr[0];
    sdir[p * 3 + 0] = dir_ij[e * 3 + 0];
    sdir[p * 3 + 1] = dir_ij[e * 3 + 1];
    sdir[p * 3 + 2] = dir_ij[e * 3 + 2];
}

// ---------------- fused edge kernel (R17/R19: barrier-free main loop) ----
// Grid (2500, 4). Block: 128 sorted edges x 64-col tile (192 W rows).
// W fragments read directly from the L2-resident fw2frag table (coalesced
// 1KB per wave-load) -> NO s_w staging, NO per-q barriers. s_h is
// wave-private. Only 2 barriers/block (s_acc init->use, use->flush).
// LDS padded to 44KB to pin 3 blocks/CU (L2-thrash guard: R8/R15/R18 all
// showed >=4 concurrent blocks/CU explodes FETCH/WRITE via L2 capacity).
__global__ __launch_bounds__(256, 3) void k_edge(
    const int* __restrict__ perm, const float* __restrict__ rbf,
    const int* __restrict__ si, const int* __restrict__ sj,
    const float* __restrict__ sfc, const float* __restrict__ sdir,
    const unsigned short* __restrict__ fw1t2, const float* __restrict__ fb1,
    const unsigned short* __restrict__ fw2frag, const float* __restrict__ fb2,
    const unsigned short* __restrict__ ctx, const unsigned short* __restrict__ vbf,
    float* __restrict__ out_s, float* __restrict__ out_v) {
    __shared__ char sm[44032];           // padded: 160KB/43KB -> 3 blocks/CU
    char* s_h = sm;                      // [128 e][128B] h-hi (swz (e&7)<<4), 16KB
    float* s_acc = (float*)(sm + 16384); // [10 rows][4 arrays][64 cols] f32, 10KB

    int g = blockIdx.x;             // edge group — dispatch-fastest
    int ct = blockIdx.y;            // col tile

    int tid = threadIdx.x;
    int lane = tid & 63, w = tid >> 6;
    int l16 = lane & 15, g4 = lane >> 4;
    int e0 = g * 128;

    for (int k2 = tid; k2 < 2560; k2 += 256) s_acc[k2] = 0.f;

    int amin = si[e0], amax = si[e0 + 127];

    // ---- rbf fragments in registers (bf16-hi), per ef ----
    bf16x8 bfr_hi[2];
#pragma unroll
    for (int ef = 0; ef < 2; ++ef) {
        int pe = perm[e0 + 32 * w + 16 * ef + l16];
        const float* rr = rbf + (size_t)pe * N_RBF;
        float xx[8];
#pragma unroll
        for (int t = 0; t < 8; ++t) xx[t] = 0.f;
        if (g4 == 0) {
            float4 a = *(const float4*)(rr);
            float4 b = *(const float4*)(rr + 4);
            xx[0]=a.x; xx[1]=a.y; xx[2]=a.z; xx[3]=a.w;
            xx[4]=b.x; xx[5]=b.y; xx[6]=b.z; xx[7]=b.w;
        } else if (g4 == 1) {
            float4 a = *(const float4*)(rr + 8);
            float4 b = *(const float4*)(rr + 12);
            xx[0]=a.x; xx[1]=a.y; xx[2]=a.z; xx[3]=a.w;
            xx[4]=b.x; xx[5]=b.y; xx[6]=b.z; xx[7]=b.w;
        } else if (g4 == 2) {
            float4 a = *(const float4*)(rr + 16);
            xx[0]=a.x; xx[1]=a.y; xx[2]=a.z; xx[3]=a.w;
        }
        union { bf16x8 v; unsigned short s[8]; } uh;
#pragma unroll
        for (int t = 0; t < 8; ++t) uh.s[t] = f2bf(xx[t]);
        bfr_hi[ef] = uh.v;
    }

    f32x4 acc[12][2];
#pragma unroll
    for (int a = 0; a < 12; a++)
#pragma unroll
        for (int b = 0; b < 2; b++) acc[a][b] = (f32x4){0.f, 0.f, 0.f, 0.f};

    for (int q = 0; q < 8; ++q) {
        // (a) issue 12 coalesced W-frag loads (L2-resident table)
        bf16x8 awf[12];
#pragma unroll
        for (int nf = 0; nf < 12; ++nf)
            awf[nf] = *(const bf16x8*)(fw2frag +
                      ((size_t)(((ct * 8 + q) * 12 + nf) * 64) + lane) * 8);
        // (b) h chunk via 2-term split MFMA (fw1 hi+lo, rbf hi), hi-only
        //     store into wave-private s_h rows (no barrier needed)
#pragma unroll
        for (int cf = 0; cf < 2; ++cf) {
            const unsigned short* ar = fw1t2 + (size_t)(q * 32 + cf * 16 + l16) * 64;
            bf16x8 ahi = *(const bf16x8*)(ar + g4 * 8);
            bf16x8 alo = *(const bf16x8*)(ar + 32 + g4 * 8);
            int cbase = cf * 16 + g4 * 4;
            float4 b1 = *(const float4*)(fb1 + q * 32 + cbase);
#pragma unroll
            for (int ef = 0; ef < 2; ++ef) {
                f32x4 ha = (f32x4){0.f, 0.f, 0.f, 0.f};
                ha = MFMA16(ahi, bfr_hi[ef], ha, 0, 0, 0);
                ha = MFMA16(alo, bfr_hi[ef], ha, 0, 0, 0);
                float h0 = silu_f(ha[0] + b1.x);
                float h1 = silu_f(ha[1] + b1.y);
                float h2 = silu_f(ha[2] + b1.z);
                float h3 = silu_f(ha[3] + b1.w);
                uint2 pk;
                pk.x = (unsigned)f2bf(h0) | ((unsigned)f2bf(h1) << 16);
                pk.y = (unsigned)f2bf(h2) | ((unsigned)f2bf(h3) << 16);
                int e = 32 * w + 16 * ef + l16;
                *(uint2*)(s_h + e * 128 + ((2 * cbase) ^ ((e & 7) << 4))) = pk;
            }
        }
        // (c) main MFMA: 1-term, 12 n-frags x 2 e-frags
        bf16x8 bh[2];
#pragma unroll
        for (int ef = 0; ef < 2; ef++) {
            int e = 32 * w + 16 * ef + l16;
            bh[ef] = *(const bf16x8*)(s_h + e * 128 + ((16 * g4) ^ ((e & 7) << 4)));
        }
#pragma unroll
        for (int nf = 0; nf < 12; nf++)
#pragma unroll
            for (int ef = 0; ef < 2; ef++)
                acc[nf][ef] = MFMA16(awf[nf], bh[ef], acc[nf][ef], 0, 0, 0);
    }

    __syncthreads();   // s_acc zero-init visible before any ds_add

    // ---------------- epilogue ----------------
#pragma unroll
    for (int ef = 0; ef < 2; ++ef) {
        int E = e0 + 32 * w + 16 * ef + l16;
        int ai = si[E], aj = sj[E];
        float fc = sfc[E];
        float d0 = sdir[3 * E], d1 = sdir[3 * E + 1], d2 = sdir[3 * E + 2];
        int i1 = __shfl_down(ai, 1, 16), i2 = __shfl_down(ai, 2, 16);
        int i4 = __shfl_down(ai, 4, 16), i8 = __shfl_down(ai, 8, 16);
        int prevai = __shfl_up(ai, 1, 16);
        bool m1 = (l16 + 1 < 16) && (i1 == ai);
        bool m2 = (l16 + 2 < 16) && (i2 == ai);
        bool m4 = (l16 + 4 < 16) && (i4 == ai);
        bool m8 = (l16 + 8 < 16) && (i8 == ai);
        bool lead = (l16 == 0) || (prevai != ai);
        int row = ai - amin;
        // LDS accumulator row: 0-7 interior, 8 = amin, 9 = amax, -1 = fallback
        int accrow = (ai == amin) ? 8 : (ai == amax) ? 9 : (row <= 8 ? row - 1 : -1);
        const unsigned short* cj = ctx + (size_t)aj * H3;
        const unsigned short* vj = vbf + (size_t)aj * H3;
#pragma unroll
        for (int ci = 0; ci < 4; ++ci) {
            int Cb = ct * 64 + ci * 16 + g4 * 4;
            ushort4 c0u = *(const ushort4*)(cj + Cb);
            ushort4 c1u = *(const ushort4*)(cj + H + Cb);
            ushort4 c2u = *(const ushort4*)(cj + 2 * H + Cb);
            ushort4 u0u = *(const ushort4*)(vj + Cb);
            ushort4 u1u = *(const ushort4*)(vj + H + Cb);
            ushort4 u2u = *(const ushort4*)(vj + 2 * H + Cb);
            float4 b0 = *(const float4*)(fb2 + Cb);
            float4 b1 = *(const float4*)(fb2 + H + Cb);
            float4 b2 = *(const float4*)(fb2 + 2 * H + Cb);
            float c0f[4] = { bf2f(c0u.x), bf2f(c0u.y), bf2f(c0u.z), bf2f(c0u.w) };
            float c1f[4] = { bf2f(c1u.x), bf2f(c1u.y), bf2f(c1u.z), bf2f(c1u.w) };
            float c2f[4] = { bf2f(c2u.x), bf2f(c2u.y), bf2f(c2u.z), bf2f(c2u.w) };
            float u0f[4] = { bf2f(u0u.x), bf2f(u0u.y), bf2f(u0u.z), bf2f(u0u.w) };
            float u1f[4] = { bf2f(u1u.x), bf2f(u1u.y), bf2f(u1u.z), bf2f(u1u.w) };
            float u2f[4] = { bf2f(u2u.x), bf2f(u2u.y), bf2f(u2u.z), bf2f(u2u.w) };
            float vds[4], vv0[4], vv1[4], vv2[4];
#pragma unroll
            for (int r = 0; r < 4; ++r) {
                float w0 = acc[ci][ef][r]     + ((const float*)&b0)[r];
                float w1 = acc[4 + ci][ef][r] + ((const float*)&b1)[r];
                float w2 = acc[8 + ci][ef][r] + ((const float*)&b2)[r];
                float ds  = c0f[r] * w0 * fc;
                float dvs = c1f[r] * w1 * fc;
                float dvv = c2f[r] * w2 * fc;
                vds[r] = ds;
                vv0[r] = dvs * d0 + dvv * u0f[r];
                vv1[r] = dvs * d1 + dvv * u1f[r];
                vv2[r] = dvs * d2 + dvv * u2f[r];
            }
#pragma unroll
            for (int st = 0; st < 4; ++st) {
                int off = 1 << st;
                bool mm = (st == 0) ? m1 : (st == 1) ? m2 : (st == 2) ? m4 : m8;
#pragma unroll
                for (int r = 0; r < 4; ++r) {
                    float t0 = __shfl_down(vds[r], off, 16);
                    float t1 = __shfl_down(vv0[r], off, 16);
                    float t2 = __shfl_down(vv1[r], off, 16);
                    float t3 = __shfl_down(vv2[r], off, 16);
                    if (mm) { vds[r] += t0; vv0[r] += t1; vv1[r] += t2; vv2[r] += t3; }
                }
            }
            if (lead) {
                if (accrow >= 0) {
                    int base = accrow * 256;     // 4 arrays x 64 cols
                    int cl = ci * 16 + g4 * 4;
#pragma unroll
                    for (int r = 0; r < 4; ++r) {
                        atomicAdd(&s_acc[base + 0 * 64 + cl + r], vds[r]);
                        atomicAdd(&s_acc[base + 1 * 64 + cl + r], vv0[r]);
                        atomicAdd(&s_acc[base + 2 * 64 + cl + r], vv1[r]);
                        atomicAdd(&s_acc[base + 3 * 64 + cl + r], vv2[r]);
                    }
                } else {
#pragma unroll
                    for (int r = 0; r < 4; ++r) {
                        int C = Cb + r;
                        atomicAdd(&out_s[(size_t)ai * H + C], vds[r]);
                        atomicAdd(&out_v[(size_t)ai * H3 + C], vv0[r]);
                        atomicAdd(&out_v[(size_t)ai * H3 + H + C], vv1[r]);
                        atomicAdd(&out_v[(size_t)ai * H3 + 2 * H + C], vv2[r]);
                    }
                }
            }
        }
    }

    // ---- flush: interior rows plain RMW (sole writer); amin/amax atomic ----
    __syncthreads();
    for (int s5 = tid; s5 < 2560; s5 += 256) {
        float val = s_acc[s5];
        if (val != 0.f) {
            int cl = s5 & 63;
            int arr = (s5 >> 6) & 3;
            int rr = s5 >> 8;                 // 0..9
            int C = ct * 64 + cl;
            if (rr < 8) {
                int atom = amin + 1 + rr;     // exclusively owned
                if (arr == 0) {
                    float* p = &out_s[(size_t)atom * H + C];
                    *p = *p + val;
                } else {
                    float* p = &out_v[(size_t)atom * H3 + (arr - 1) * H + C];
                    *p = *p + val;
                }
            } else {
                int atom = (rr == 8) ? amin : amax;   // shared boundary
                if (arr == 0) atomicAdd(&out_s[(size_t)atom * H + C], val);
                else atomicAdd(&out_v[(size_t)atom * H3 + (arr - 1) * H + C], val);
            }
        }
    }
}

extern "C" void kernel_launch(void* const* d_in, const int* in_sizes, int n_in,
                              void* d_out, int out_size, void* d_ws, size_t ws_size,
                              hipStream_t stream) {
    const float* s      = (const float*)d_in[0];
    const float* v      = (const float*)d_in[1];
    const int*   idx_i  = (const int*)d_in[2];
    const int*   idx_j  = (const int*)d_in[3];
    const float* rbf    = (const float*)d_in[4];
    const float* f_cut  = (const float*)d_in[5];
    const float* dir_ij = (const float*)d_in[6];
    const float* inv    = (const float*)d_in[7];
    const float* ln_g   = (const float*)d_in[8];
    const float* ln_b   = (const float*)d_in[9];
    const float* cw1    = (const float*)d_in[10];
    const float* cb1    = (const float*)d_in[11];
    const float* cw2    = (const float*)d_in[12];
    const float* cb2    = (const float*)d_in[13];
    const float* fw1    = (const float*)d_in[14];
    const float* fb1    = (const float*)d_in[15];
    const float* fw2    = (const float*)d_in[16];
    const float* fb2    = (const float*)d_in[17];

    float* out_s = (float*)d_out;
    float* out_v = out_s + (size_t)N_ATOMS * H;

    // ---- ws layout (bytes), peak 47,415,296 (< 51.2MB proven) ----
    char* wsb = (char*)d_ws;
    unsigned short* fw2frag  = (unsigned short*)(wsb + 0);          //    393,216
    unsigned short* fw1t2    = (unsigned short*)(wsb + 393216);     //     32,768
    int*            counts   = (int*)(wsb + 425984);                //     40,960
    int*            rowstart = (int*)(wsb + 466944);                //     40,960
    int*            cursor   = (int*)(wsb + 507904);                //     40,960
    unsigned short* vbf      = (unsigned short*)(wsb + 548864);     // 15,360,000 bf16
    unsigned short* ctx      = (unsigned short*)(wsb + 15908864);   // 15,360,000 bf16
    float*          sn       = (float*)(wsb + 31268864);            // 10,240,000
    unsigned short* ctx1     = (unsigned short*)(wsb + 41508864);   //  5,120,000 bf16
    unsigned short* cw2frag2 = (unsigned short*)(wsb + 46628864);   //    786,432
    // overlays of sn region (written only after gemm1 consumed sn):
    int*            perm     = (int*)(wsb + 31268864);              //  1,280,000
    int*            si       = (int*)(wsb + 32548864);
    int*            sj       = (int*)(wsb + 33828864);
    float*          sfc      = (float*)(wsb + 35108864);
    float*          sdir     = (float*)(wsb + 36388864);            //  3,840,000

    // init outputs with s, v (updates accumulated on top)
    hipMemcpyAsync(out_s, s, sizeof(float) * (size_t)N_ATOMS * H,
                   hipMemcpyDeviceToDevice, stream);
    hipMemcpyAsync(out_v, v, sizeof(float) * (size_t)N_ATOMS * 3 * H,
                   hipMemcpyDeviceToDevice, stream);
    hipMemsetAsync(counts, 0, 122880, stream);   // counts+rowstart+cursor

    // weight prep + v->bf16 + histogram
    k_prep_fw2frag<<<96, 256, 0, stream>>>(fw2, fw2frag);
    k_prep_cw2frag<<<96, 256, 0, stream>>>(cw2, cw2frag2);
    k_prep_fw1t2<<<1, 256, 0, stream>>>(fw1, fw1t2);
    k_prep_vbf<<<7500, 256, 0, stream>>>(v, vbf);     // 7.68M = 7500*1024
    k_hist<<<(N_EDGES + 255) / 256, 256, 0, stream>>>(idx_i, counts);
    k_scan<<<1, 256, 0, stream>>>(counts, rowstart);

    // context path (uses sn, then ctx1, then ctx)
    k_ln<<<N_ATOMS, 256, 0, stream>>>(s, ln_g, ln_b, sn);
    dim3 g1((N_ATOMS + 63) / 64, H / 64);
    k_gemm<1, 0, 1><<<g1, 256, 0, stream>>>(sn, cw1, cb1, ctx1, N_ATOMS, H, H);

    // fused scatter+gather (overlays sn, dead now)
    k_scatter<<<(N_EDGES + 255) / 256, 256, 0, stream>>>(
        idx_i, idx_j, f_cut, dir_ij, inv, rowstart, cursor,
        perm, si, sj, sfc, sdir);

    // gemm2 via MFMA (barrier-free, LDS-free)
    dim3 g2((N_ATOMS + 63) / 64, 8);
    k_gemm2_mfma<<<g2, 256, 0, stream>>>(ctx1, cw2frag2, cb2, ctx);

    // fused edge GEMM + scatter — x = edge group (dispatch-fastest)
    dim3 ge(2500, 4);
    k_edge<<<ge, 256, 0, stream>>>(perm, rbf, si, sj, sfc, sdir, fw1t2, fb1,
                                   fw2frag, fb2, ctx, vbf, out_s, out_v);
}